// Round 8
// baseline (411.413 us; speedup 1.0000x reference)
//
#include <hip/hip_runtime.h>
#include <stdint.h>

#define RH 224
#define RW 224

// Zero-workspace scheme: d_out itself holds the per-pixel winner order (u32)
// during pass 1, then pass 2 replaces it in-place with the winner's depth.
//
// FP policy: bit-match numpy f32 einsum (ref=np). numpy's einsum_sumprod
// (contig_outstride0_two) is compiled with BASELINE SSE2 flags (einsum has no
// SIMD dispatch); count=3 < vstep skips the vector loop and the scalar tail
// runs FORWARD with separate mul/add rounds (baseline SSE2 has no FMA):
//   accum  = v0*R0; accum += v1*R1; accum += v2*R2;  // ((p0+p1)+p2)
// then translation add, +1e-8, div, mul, add as separate numpy ufuncs.
// `#pragma clang fp contract(off)` pins hipcc (default fast-honor-pragmas)
// to one correctly-rounded instruction per op — round 7 proved the pragma
// changes codegen (absmax moved 2.5156 -> 2.3594 vs the contracted build).

#pragma clang fp contract(off)

__device__ __forceinline__ float dot3_fwd_nofma(float v0, float v1, float v2,
                                                const float* __restrict__ R,
                                                float t) {
#pragma clang fp contract(off)
    const float p0 = v0 * R[0];
    const float p1 = v1 * R[1];
    const float p2 = v2 * R[2];
    float acc = p0 + p1;
    acc = acc + p2;
    acc = acc + t;
    return acc;
}

// Pass 1: per-point projection; atomicMax of (order+1) into d_out (as u32).
__global__ void proj_kernel(const float* __restrict__ vertices,
                            const float* __restrict__ rotation,
                            const float* __restrict__ translation,
                            const float* __restrict__ Kmat,
                            unsigned int* __restrict__ win,  // = d_out as u32
                            int N) {
#pragma clang fp contract(off)
    const int b = blockIdx.y;
    const int n = blockIdx.x * blockDim.x + threadIdx.x;
    if (n >= N) return;

    // Per-batch params: b is block-uniform -> scalar loads.
    const float* R = rotation + b * 9;
    const float* t = translation + b * 3;
    const float* k = Kmat + b * 9;
    const float fx = k[0], cx = k[2], fy = k[4], cy = k[5];

    const float* v = vertices + ((size_t)b * (size_t)N + (size_t)n) * 3;
    const float v0 = v[0], v1 = v[1], v2 = v[2];

    const float x = dot3_fwd_nofma(v0, v1, v2, R + 0, t[0]);
    const float y = dot3_fwd_nofma(v0, v1, v2, R + 3, t[1]);
    const float z = dot3_fwd_nofma(v0, v1, v2, R + 6, t[2]);

    const float Z = z + 1e-8f;          // separate round
    const float qx = x / Z;             // correctly-rounded f32 div
    const float qy = y / Z;
    float u = fx * qx;                  // separate mul
    u = u + cx;                         // separate add (contract off -> no fma)
    float w = fy * qy;
    w = w + cy;

    // trunc toward zero; validity on the truncated float. u in (-1,0) -> -0.0,
    // -0.0 >= 0.0 is true, matching numpy trunc->astype(int32); huge/NaN ->
    // INT32_MIN in numpy, fails the range compare here: same outcome.
    const float tu = truncf(u);
    const float tv = truncf(w);
    if (tu >= 0.0f && tu < (float)RW && tv >= 0.0f && tv < (float)RH) {
        const int ui = (int)tu;
        const int vi = (int)tv;
        const int pix = b * (RH * RW) + vi * RW + ui;
        const unsigned int order1 = (unsigned int)(b * N + n) + 1u;  // 0 == empty
        atomicMax(&win[pix], order1);
    }
}

// Pass 2: in-place decode winner order -> depth (recomputed with the identical
// FP sequence). Empty pixels (order 0) -> 0.0f.
__global__ void resolve_kernel(unsigned int* __restrict__ buf,  // = d_out
                               const float* __restrict__ vertices,
                               const float* __restrict__ rotation,
                               const float* __restrict__ translation,
                               int N, int P) {
#pragma clang fp contract(off)
    const int i = blockIdx.x * blockDim.x + threadIdx.x;
    if (i >= P) return;
    const unsigned int o1 = buf[i];
    float depth = 0.0f;
    if (o1 != 0u) {
        const unsigned int o = o1 - 1u;
        const int b = (int)(o / (unsigned int)N);
        const int n = (int)(o % (unsigned int)N);
        const float* v = vertices + ((size_t)b * (size_t)N + (size_t)n) * 3;
        const float* R = rotation + b * 9;
        depth = dot3_fwd_nofma(v[0], v[1], v[2], R + 6, translation[b * 3 + 2]);
    }
    buf[i] = __float_as_uint(depth);  // final f32 image, written as bits
}

extern "C" void kernel_launch(void* const* d_in, const int* in_sizes, int n_in,
                              void* d_out, int out_size, void* d_ws, size_t ws_size,
                              hipStream_t stream) {
    const float* vertices    = (const float*)d_in[0];
    const float* rotation    = (const float*)d_in[1];
    const float* translation = (const float*)d_in[2];
    const float* Kmat        = (const float*)d_in[3];

    const int B = in_sizes[1] / 9;              // rotation is B*3*3
    const int N = in_sizes[0] / (3 * B);        // vertices is B*N*3
    const int P = B * RH * RW;                  // == out_size

    unsigned int* win = (unsigned int*)d_out;

    // d_out must start at 0 every call (harness poisons once, never restores).
    hipMemsetAsync(win, 0, (size_t)P * sizeof(unsigned int), stream);

    dim3 block(256);
    dim3 grid((N + 255) / 256, B);
    proj_kernel<<<grid, block, 0, stream>>>(vertices, rotation, translation, Kmat, win, N);

    const int rblocks = (P + 255) / 256;
    resolve_kernel<<<rblocks, 256, 0, stream>>>(win, vertices, rotation, translation, N, P);
}